// Round 9
// baseline (2218.600 us; speedup 1.0000x reference)
//
#include <hip/hip_runtime.h>
#include <hip/hip_bf16.h>

typedef __attribute__((ext_vector_type(4))) float f32x4;
typedef __attribute__((ext_vector_type(4))) int   i32x4;
typedef __attribute__((ext_vector_type(8))) short s16x8;
typedef __attribute__((ext_vector_type(4))) unsigned short u16x4;
typedef __attribute__((ext_vector_type(2))) unsigned int  u32x2;

#define T_ 512
#define B_ 8
#define H_ 128
#define V_ 32000

// ws layout (bytes)
#define WS_PRE0   0u          // [512][8][128] f32   2MB
#define WS_H1B    (2u<<20)    // [512][8][128] bf16  1MB
#define WS_H0G    (3u<<20)    // [512][8][128] bf16  1MB
#define WS_PIH    (4u<<20)    // [512][8 mt][64 lane] f32x4  4MB
#define WS_FLAGS  (8u<<20)    // prog0 @+0, prog1[4] @+256, prog2 @+512

#define NW 253                // gemm worker blocks
#define NTILES 8000           // 4 tb x 250 nt x 8 bb

// round-to-nearest-even f32 -> bf16
__device__ __forceinline__ unsigned short f2b(float f) {
  unsigned int u = __float_as_uint(f);
  u = (u + 0x7FFFu + ((u >> 16) & 1u)) >> 16;
  return (unsigned short)u;
}

__device__ __forceinline__ float hsum4(f32x4 v) { return (v.x + v.y) + (v.z + v.w); }

__device__ __forceinline__ float tanh_fast(float x) {
  float e = __expf(2.f * x);
  return 1.f - 2.f * __builtin_amdgcn_rcpf(e + 1.f);
}

__device__ __forceinline__ f32x4 tanh4(f32x4 v) {
  f32x4 r;
  r.x = tanh_fast(v.x); r.y = tanh_fast(v.y);
  r.z = tanh_fast(v.z); r.w = tanh_fast(v.w);
  return r;
}

// pack 4 f32 -> 4 bf16 (2 dwords), RNE
__device__ __forceinline__ u32x2 pk4(f32x4 v) {
  unsigned int a, b;
  asm("v_cvt_pk_bf16_f32 %0, %1, %2" : "=v"(a) : "v"(v.x), "v"(v.y));
  asm("v_cvt_pk_bf16_f32 %0, %1, %2" : "=v"(b) : "v"(v.z), "v"(v.w));
  u32x2 r; r.x = a; r.y = b; return r;
}

// barrier that does NOT drain vmcnt: LDS-only visibility + s_barrier.
__device__ __forceinline__ void lds_barrier() {
  asm volatile("s_waitcnt lgkmcnt(0)\n\ts_barrier" ::: "memory");
}

__device__ __forceinline__ unsigned int ld_flag_acq(const unsigned int* p) {
  return __hip_atomic_load(p, __ATOMIC_ACQUIRE, __HIP_MEMORY_SCOPE_AGENT);
}
__device__ __forceinline__ void flag_add_rel(unsigned int* p, unsigned int v) {
  __hip_atomic_fetch_add(p, v, __ATOMIC_RELEASE, __HIP_MEMORY_SCOPE_AGENT);
}

#define MFMA16(A, B, C) __builtin_amdgcn_mfma_f32_16x16x32_bf16((A), (B), (C), 0, 0, 0)

__device__ __forceinline__ int swz(int row, int cc) {
  return row * 256 + ((cc ^ (row & 7)) << 4);
}

// ---------------- pre0 = emb[x] @ W_ih0^T + b_ih0 + b_hh0 ----------------
__global__ __launch_bounds__(128) void pre_kernel(const float* __restrict__ emb,
                                                  const int* __restrict__ x,
                                                  const float* __restrict__ W,
                                                  const float* __restrict__ b1,
                                                  const float* __restrict__ b2,
                                                  float* __restrict__ out) {
  const int tid = threadIdx.x;
  __shared__ alignas(16) float lds_in[H_];
  f32x4 w[32];
#pragma unroll
  for (int r = 0; r < 32; ++r) w[r] = *(const f32x4*)(W + tid * H_ + 4 * r);
  const float bsum = b1[tid] + b2[tid];
  const int m0 = blockIdx.x * 16;

  auto src_row = [&](int m) -> const float* {
    int t = m >> 3, b = m & 7;
    int tok = x[(b << 9) + t];          // x is [B,T]
    return emb + (size_t)tok * H_;
  };

  float stage = src_row(m0)[tid];
  for (int rr = 0; rr < 16; ++rr) {
    const int m = m0 + rr;
    lds_in[tid] = stage;
    __syncthreads();
    if (rr + 1 < 16) stage = src_row(m0 + rr + 1)[tid];
    f32x4 acc4 = {0.f, 0.f, 0.f, 0.f};
#pragma unroll
    for (int r = 0; r < 32; ++r) {
      f32x4 hv = *(const f32x4*)(lds_in + 4 * r);
      acc4 = __builtin_elementwise_fma(hv, w[r], acc4);
    }
    out[m * H_ + tid] = hsum4(acc4) + bsum;
    __syncthreads();
  }
}

// ---------------- mega kernel v2 ----------------
// 131072B static LDS => exactly 1 block/CU: scan blocks (0,1,2) get dedicated
// CUs; 253 gemm workers own the rest. waves_per_eu(1,1): full VGPR budget.
// block 0 = stage0: h0 recurrence, 4 waves x 2 M-tiles (16 MFMA, 16 ds_read);
//   publishes prog0 += 8 per 8 steps (vmcnt(0)+barrier first).
// block 1 = stage1: pih = W_ih1.h0 + b (hi-only). 4 independent waves, NO
//   barriers; per-wave flags prog1[w] += 8 after vmcnt(0).
// block 2 = stage2: h1 recurrence (like stage0), polls min(prog1[0..3]);
//   publishes prog2 += 32 per 32 steps for the gemm workers; writes h1b.
// blocks 3..255: gemm workers, tiles idx = wb + i*253 (tb-major ascending),
//   stage fc_W f32->bf16 swizzled, gate on prog2 >= (tb+1)*128, MFMA,
//   LDS-transposed 256B-segment nontemporal stores.
__global__ __launch_bounds__(256) __attribute__((amdgpu_waves_per_eu(1, 1)))
void mega2(const float* __restrict__ pre0,
           const float* __restrict__ W_hh0,
           const float* __restrict__ W_ih1,
           const float* __restrict__ W_hh1,
           const float* __restrict__ b_ih1,
           const float* __restrict__ b_hh1,
           unsigned short* __restrict__ h0g,
           float* __restrict__ pih_raw,
           unsigned short* __restrict__ h1b,
           unsigned int* __restrict__ prog0,
           unsigned int* __restrict__ prog1,
           unsigned int* __restrict__ prog2,
           const float* __restrict__ fc_W,
           const float* __restrict__ fc_b,
           float* __restrict__ out) {
  __shared__ alignas(16) char smem[131072];
  const int bid = blockIdx.x;
  const int tid = threadIdx.x;
  const int wv = tid >> 6, lane = tid & 63;
  const f32x4 z4 = {0.f, 0.f, 0.f, 0.f};

  if (bid >= 3) {
    // ================= gemm workers =================
    const int wb = bid - 3;
    const int l15 = lane & 15, lg = lane >> 4;
    int known = 0;
    for (int tile = wb; tile < NTILES; tile += NW) {
      const int tb = tile / 2000, r = tile - tb * 2000;
      const int nt = r >> 3, bb = r & 7;
      const int t0 = tb << 7, v0 = nt << 7;

      // stage fcW tile f32 -> bf16, swizzled (32KB)
#pragma unroll
      for (int it = 0; it < 8; ++it) {
        int c = it * 256 + tid;
        int row = c >> 4, cc = c & 15;
        const float* src = fc_W + (size_t)(v0 + row) * H_ + cc * 8;
        f32x4 va = *(const f32x4*)src;
        f32x4 vb = *(const f32x4*)(src + 4);
        u32x2 pa = pk4(va), pb = pk4(vb);
        i32x4 w16; w16.x = (int)pa.x; w16.y = (int)pa.y; w16.z = (int)pb.x; w16.w = (int)pb.y;
        *(i32x4*)(smem + swz(row, cc)) = w16;
      }
      // gate on h1 progress
      const int need = (tb + 1) * 128;
      if (tid == 0 && known < need) {
        unsigned int p;
        while ((int)(p = ld_flag_acq(prog2)) < need) __builtin_amdgcn_s_sleep(32);
        known = (int)p;
      }
      __syncthreads();

      f32x4 acc[8][2] = {};   // [vf][mf]
#pragma unroll
      for (int kk = 0; kk < 4; ++kk) {
        const int cc = kk * 4 + lg;
        s16x8 a[8], bfr[2];
#pragma unroll
        for (int vf = 0; vf < 8; ++vf)
          a[vf] = *(const s16x8*)(smem + swz(vf * 16 + l15, cc));
#pragma unroll
        for (int mf = 0; mf < 2; ++mf) {
          int trow = t0 + wv * 32 + mf * 16 + l15;
          bfr[mf] = *(const s16x8*)(h1b + (size_t)((trow << 3) + bb) * H_ + kk * 32 + lg * 8);
        }
#pragma unroll
        for (int vf = 0; vf < 8; ++vf)
#pragma unroll
          for (int mf = 0; mf < 2; ++mf)
            acc[vf][mf] = MFMA16(a[vf], bfr[mf], acc[vf][mf]);
      }
#pragma unroll
      for (int vf = 0; vf < 8; ++vf) {
        f32x4 bv = *(const f32x4*)(fc_b + v0 + vf * 16 + (lg << 2));
#pragma unroll
        for (int mf = 0; mf < 2; ++mf) acc[vf][mf] += bv;
      }

      float* tbf = (float*)smem;
#pragma unroll
      for (int p = 0; p < 2; ++p) {
        __syncthreads();
#pragma unroll
        for (int q = 0; q < 4; ++q) {
          const int vf = p * 4 + q;
#pragma unroll
          for (int mf = 0; mf < 2; ++mf)
            *(f32x4*)(tbf + (wv * 32 + mf * 16 + l15) * 66 + q * 16 + lg * 4) = acc[vf][mf];
        }
        __syncthreads();
#pragma unroll
        for (int it = 0; it < 8; ++it) {
          int row = it * 16 + (tid >> 4);
          int col = (tid & 15) * 4;
          f32x4 val = *(const f32x4*)(tbf + row * 66 + col);
          const size_t off = (size_t)((bb << 9) + t0 + row) * V_ + v0 + p * 64 + col;
          __builtin_nontemporal_store(val, (f32x4*)(out + off));
        }
      }
      __syncthreads();   // before restaging W over tbf
    }
    return;
  }

  // ================= scan blocks =================
  typedef unsigned short (*HLP)[16][136];
  HLP hl = (HLP)smem;              // [2][16][136] bf16
  const int n = lane & 15, g = lane >> 4;
  const int nn = (n < 8) ? n : 7;
  const int w = wv;                // 4 waves, wave w owns M-tiles 2w, 2w+1
  const int m0 = w * 32;
  f32x4* pih_gf = (f32x4*)pih_raw;

  if (bid == 0) {
    // ---- stage 0: h0 recurrence ----
    for (int i = tid; i < 2 * 16 * 136; i += 256) ((unsigned short*)smem)[i] = 0;
    s16x8 whi[2][4], wlo[2][4];
#pragma unroll
    for (int hf = 0; hf < 2; ++hf)
#pragma unroll
      for (int kt = 0; kt < 4; ++kt) {
        const float* src = W_hh0 + (m0 + hf * 16 + n) * H_ + kt * 32 + g * 8;
        s16x8 hi, lo;
#pragma unroll
        for (int j = 0; j < 8; ++j) {
          float v = src[j];
          unsigned short hb = f2b(v);
          hi[j] = (short)hb;
          lo[j] = (short)f2b(v - __uint_as_float(((unsigned int)hb) << 16));
        }
        whi[hf][kt] = hi; wlo[hf][kt] = lo;
      }
    f32x4 fif[4][2];
#pragma unroll
    for (int k = 0; k < 4; ++k) {
      fif[k][0] = *(const f32x4*)(pre0 + ((k * 8 + nn) << 7) + m0 + g * 4);
      fif[k][1] = *(const f32x4*)(pre0 + ((k * 8 + nn) << 7) + m0 + 16 + g * 4);
    }
    __syncthreads();

    for (int s = 0; s < T_; ++s) {
      const int rd = (s + 1) & 1, wr = s & 1;
      const unsigned short* hb = &hl[rd][n][0];
      s16x8 b0 = *(const s16x8*)(hb + g * 8);
      s16x8 b1 = *(const s16x8*)(hb + 32 + g * 8);
      s16x8 b2 = *(const s16x8*)(hb + 64 + g * 8);
      s16x8 b3 = *(const s16x8*)(hb + 96 + g * 8);
      // half 0
      f32x4 hA = MFMA16(whi[0][0], b0, fif[s & 3][0]);
      f32x4 hB = MFMA16(whi[0][2], b2, z4);
      f32x4 lA = MFMA16(wlo[0][0], b0, z4);
      f32x4 lB = MFMA16(wlo[0][2], b2, z4);
      hA = MFMA16(whi[0][1], b1, hA);
      hB = MFMA16(whi[0][3], b3, hB);
      lA = MFMA16(wlo[0][1], b1, lA);
      lB = MFMA16(wlo[0][3], b3, lB);
      // half 1
      f32x4 hC = MFMA16(whi[1][0], b0, fif[s & 3][1]);
      f32x4 hD = MFMA16(whi[1][2], b2, z4);
      f32x4 lC = MFMA16(wlo[1][0], b0, z4);
      f32x4 lD = MFMA16(wlo[1][2], b2, z4);
      hC = MFMA16(whi[1][1], b1, hC);
      hD = MFMA16(whi[1][3], b3, hD);
      lC = MFMA16(wlo[1][1], b1, lC);
      lD = MFMA16(wlo[1][3], b3, lD);
      f32x4 v0 = tanh4((hA + hB) + (lA + lB));
      f32x4 v1 = tanh4((hC + hD) + (lC + lD));
      u32x2 o0 = pk4(v0), o1 = pk4(v1);
      *(u32x2*)&hl[wr][n][m0 + g * 4] = o0;
      *(u32x2*)&hl[wr][n][m0 + 16 + g * 4] = o1;
      if (n < 8) {
        *(u32x2*)(h0g + ((s * 8 + n) << 7) + m0 + g * 4) = o0;
        *(u32x2*)(h0g + ((s * 8 + n) << 7) + m0 + 16 + g * 4) = o1;
      }
      int sp = s + 4; if (sp > T_ - 1) sp = T_ - 1;
      fif[s & 3][0] = *(const f32x4*)(pre0 + ((sp * 8 + nn) << 7) + m0 + g * 4);
      fif[s & 3][1] = *(const f32x4*)(pre0 + ((sp * 8 + nn) << 7) + m0 + 16 + g * 4);
      if ((s & 7) == 7) {
        asm volatile("s_waitcnt vmcnt(0)" ::: "memory");
        lds_barrier();
        if (tid == 0) flag_add_rel(prog0, 8u);
      } else {
        lds_barrier();
      }
    }
  } else if (bid == 1) {
    // ---- stage 1: pih (hi-only), 4 independent waves, no barriers ----
    s16x8 whi[2][4];
#pragma unroll
    for (int hf = 0; hf < 2; ++hf)
#pragma unroll
      for (int kt = 0; kt < 4; ++kt) {
        const float* src = W_ih1 + (m0 + hf * 16 + n) * H_ + kt * 32 + g * 8;
        s16x8 hi;
#pragma unroll
        for (int j = 0; j < 8; ++j) hi[j] = (short)f2b(src[j]);
        whi[hf][kt] = hi;
      }
    const f32x4 bias0 = *(const f32x4*)(b_ih1 + m0 + g * 4) +
                        *(const f32x4*)(b_hh1 + m0 + g * 4);
    const f32x4 bias1 = *(const f32x4*)(b_ih1 + m0 + 16 + g * 4) +
                        *(const f32x4*)(b_hh1 + m0 + 16 + g * 4);

    while (ld_flag_acq(prog0) < 16u) __builtin_amdgcn_s_sleep(8);
    s16x8 fb[4][4];   // [slot][kt]
#pragma unroll
    for (int k = 0; k < 4; ++k)
#pragma unroll
      for (int kt = 0; kt < 4; ++kt)
        fb[k][kt] = *(const s16x8*)(h0g + ((k * 8 + nn) << 7) + kt * 32 + g * 8);

    for (int j = 0; j < T_; ++j) {
      if ((j & 7) == 0 && j > 0) {
        unsigned int req = (unsigned)(j + 16); if (req > 512u) req = 512u;
        while (ld_flag_acq(prog0) < req) __builtin_amdgcn_s_sleep(8);
      }
      const int sl = j & 3;
      f32x4 a0 = MFMA16(whi[0][0], fb[sl][0], bias0);
      f32x4 a1 = MFMA16(whi[0][2], fb[sl][2], z4);
      f32x4 c0 = MFMA16(whi[1][0], fb[sl][0], bias1);
      f32x4 c1 = MFMA16(whi[1][2], fb[sl][2], z4);
      a0 = MFMA16(whi[0][1], fb[sl][1], a0);
      a1 = MFMA16(whi[0][3], fb[sl][3], a1);
      c0 = MFMA16(whi[1][1], fb[sl][1], c0);
      c1 = MFMA16(whi[1][3], fb[sl][3], c1);
      f32x4 v0 = a0 + a1, v1 = c0 + c1;
      pih_gf[(size_t)(j * 8 + 2 * w) * 64 + n * 4 + g] = v0;
      pih_gf[(size_t)(j * 8 + 2 * w + 1) * 64 + n * 4 + g] = v1;
      int jp = j + 4;
      if (jp < T_) {
#pragma unroll
        for (int kt = 0; kt < 4; ++kt)
          fb[sl][kt] = *(const s16x8*)(h0g + ((jp * 8 + nn) << 7) + kt * 32 + g * 8);
      }
      if ((j & 7) == 7) {
        asm volatile("s_waitcnt vmcnt(0)" ::: "memory");
        if (lane == 0) flag_add_rel(prog1 + w, 8u);
      }
    }
  } else {
    // ---- stage 2: h1 recurrence ----
    for (int i = tid; i < 2 * 16 * 136; i += 256) ((unsigned short*)smem)[i] = 0;
    s16x8 whi[2][4], wlo[2][4];
#pragma unroll
    for (int hf = 0; hf < 2; ++hf)
#pragma unroll
      for (int kt = 0; kt < 4; ++kt) {
        const float* src = W_hh1 + (m0 + hf * 16 + n) * H_ + kt * 32 + g * 8;
        s16x8 hi, lo;
#pragma unroll
        for (int j = 0; j < 8; ++j) {
          float v = src[j];
          unsigned short hb = f2b(v);
          hi[j] = (short)hb;
          lo[j] = (short)f2b(v - __uint_as_float(((unsigned int)hb) << 16));
        }
        whi[hf][kt] = hi; wlo[hf][kt] = lo;
      }

    auto poll1 = [&](unsigned int req) {
      while (__any(ld_flag_acq(prog1 + (lane & 3)) < req)) __builtin_amdgcn_s_sleep(8);
    };
    poll1(16u);
    f32x4 pf[4][2];
#pragma unroll
    for (int k = 0; k < 4; ++k) {
      pf[k][0] = pih_gf[(size_t)(k * 8 + 2 * w) * 64 + n * 4 + g];
      pf[k][1] = pih_gf[(size_t)(k * 8 + 2 * w + 1) * 64 + n * 4 + g];
    }
    __syncthreads();

    for (int j = 0; j < T_; ++j) {
      if ((j & 7) == 0 && j > 0) {
        unsigned int req = (unsigned)(j + 16); if (req > 512u) req = 512u;
        poll1(req);
      }
      const int rd = (j + 1) & 1, wr = j & 1;
      const unsigned short* hb = &hl[rd][n][0];
      s16x8 b0 = *(const s16x8*)(hb + g * 8);
      s16x8 b1 = *(const s16x8*)(hb + 32 + g * 8);
      s16x8 b2 = *(const s16x8*)(hb + 64 + g * 8);
      s16x8 b3 = *(const s16x8*)(hb + 96 + g * 8);
      f32x4 hA = MFMA16(whi[0][0], b0, pf[j & 3][0]);
      f32x4 hB = MFMA16(whi[0][2], b2, z4);
      f32x4 lA = MFMA16(wlo[0][0], b0, z4);
      f32x4 lB = MFMA16(wlo[0][2], b2, z4);
      hA = MFMA16(whi[0][1], b1, hA);
      hB = MFMA16(whi[0][3], b3, hB);
      lA = MFMA16(wlo[0][1], b1, lA);
      lB = MFMA16(wlo[0][3], b3, lB);
      f32x4 hC = MFMA16(whi[1][0], b0, pf[j & 3][1]);
      f32x4 hD = MFMA16(whi[1][2], b2, z4);
      f32x4 lC = MFMA16(wlo[1][0], b0, z4);
      f32x4 lD = MFMA16(wlo[1][2], b2, z4);
      hC = MFMA16(whi[1][1], b1, hC);
      hD = MFMA16(whi[1][3], b3, hD);
      lC = MFMA16(wlo[1][1], b1, lC);
      lD = MFMA16(wlo[1][3], b3, lD);
      f32x4 v0 = tanh4((hA + hB) + (lA + lB));
      f32x4 v1 = tanh4((hC + hD) + (lC + lD));
      u32x2 o0 = pk4(v0), o1 = pk4(v1);
      *(u32x2*)&hl[wr][n][m0 + g * 4] = o0;
      *(u32x2*)&hl[wr][n][m0 + 16 + g * 4] = o1;
      if (n < 8) {
        *(u32x2*)(h1b + ((j * 8 + n) << 7) + m0 + g * 4) = o0;
        *(u32x2*)(h1b + ((j * 8 + n) << 7) + m0 + 16 + g * 4) = o1;
      }
      int jp = j + 4;
      if (jp < T_) {
        pf[j & 3][0] = pih_gf[(size_t)(jp * 8 + 2 * w) * 64 + n * 4 + g];
        pf[j & 3][1] = pih_gf[(size_t)(jp * 8 + 2 * w + 1) * 64 + n * 4 + g];
      }
      if ((j & 31) == 31) {
        asm volatile("s_waitcnt vmcnt(0)" ::: "memory");
        lds_barrier();
        if (tid == 0) flag_add_rel(prog2, 32u);
      } else {
        lds_barrier();
      }
    }
  }
}

extern "C" void kernel_launch(void* const* d_in, const int* in_sizes, int n_in,
                              void* d_out, int out_size, void* d_ws, size_t ws_size,
                              hipStream_t stream) {
  const int*   x     = (const int*)d_in[0];
  const float* emb   = (const float*)d_in[1];
  const float* W_ih0 = (const float*)d_in[2];
  const float* W_hh0 = (const float*)d_in[3];
  const float* b_ih0 = (const float*)d_in[4];
  const float* b_hh0 = (const float*)d_in[5];
  const float* W_ih1 = (const float*)d_in[6];
  const float* W_hh1 = (const float*)d_in[7];
  const float* b_ih1 = (const float*)d_in[8];
  const float* b_hh1 = (const float*)d_in[9];
  const float* fc_W  = (const float*)d_in[10];
  const float* fc_b  = (const float*)d_in[11];
  float* out = (float*)d_out;

  char* ws = (char*)d_ws;
  float*          pre0  = (float*)(ws + WS_PRE0);
  unsigned short* h1b   = (unsigned short*)(ws + WS_H1B);
  unsigned short* h0g   = (unsigned short*)(ws + WS_H0G);
  float*          pih   = (float*)(ws + WS_PIH);
  unsigned int*   prog0 = (unsigned int*)(ws + WS_FLAGS);
  unsigned int*   prog1 = (unsigned int*)(ws + WS_FLAGS + 256);
  unsigned int*   prog2 = (unsigned int*)(ws + WS_FLAGS + 512);

  hipMemsetAsync(ws + WS_FLAGS, 0, 4096, stream);
  pre_kernel<<<256, 128, 0, stream>>>(emb, x, W_ih0, b_ih0, b_hh0, pre0);
  mega2<<<3 + NW, 256, 0, stream>>>(pre0, W_hh0, W_ih1, W_hh1, b_ih1, b_hh1,
                                    h0g, pih, h1b, prog0, prog1, prog2,
                                    fc_W, fc_b, out);
}